// Round 7
// baseline (282.156 us; speedup 1.0000x reference)
//
#include <hip/hip_runtime.h>
#include <stdint.h>

// Problem constants
#define S_LEN 2048
#define DMODEL 1024
#define NHEAD 16
#define DKH 64
// M for all GEMMs = B*S = 4096, N = K = 1024

typedef __attribute__((ext_vector_type(8))) short short8;
typedef __attribute__((ext_vector_type(4))) short sv4;
typedef __attribute__((ext_vector_type(4))) float fv4;
typedef __attribute__((ext_vector_type(8))) __bf16 bf16x8;
typedef __attribute__((ext_vector_type(4))) float f32x4;

// 0.125 (1/sqrt(DK)) * log2(e): folded into Wq/bq so softmax can use native exp2
#define QSCALE 0.18033688011112042f

static __device__ __forceinline__ short f2bf(float f) {
  unsigned u = __builtin_bit_cast(unsigned, f);
  u = u + 0x7fffu + ((u >> 16) & 1u);   // RNE
  return (short)(u >> 16);
}

static __device__ __forceinline__ bf16x8 ldfrag(const void* p) {
  return __builtin_bit_cast(bf16x8, *(const short8*)p);
}

#define GLL16(gp, lp) __builtin_amdgcn_global_load_lds( \
    (const __attribute__((address_space(1))) unsigned int*)(const void*)(gp), \
    (__attribute__((address_space(3))) unsigned int*)(void*)(lp), 16, 0, 0)

#define WAIT_VMCNT0() asm volatile("s_waitcnt vmcnt(0)" ::: "memory")
#define WAIT_LGKM0()  asm volatile("s_waitcnt lgkmcnt(0)" ::: "memory")

// ---------------------------------------------------------------------------
// Kernel 1: f32 -> bf16 conversion of q,k,v and Wq,Wk,Wv,Wo.
// Wq is pre-scaled by QSCALE (softmax then uses exp2 with no per-elem scale).
// ---------------------------------------------------------------------------
__global__ __launch_bounds__(256) void convert_all(
    const float* __restrict__ q, const float* __restrict__ k, const float* __restrict__ v,
    const float* __restrict__ wq, const float* __restrict__ wk, const float* __restrict__ wv,
    const float* __restrict__ wo,
    short* __restrict__ xb, short* __restrict__ wb, short* __restrict__ wob)
{
  const int total = 4194304;  // float4 groups: 3*(4M/4) + 4*(1M/4)
  for (int gid = blockIdx.x * blockDim.x + threadIdx.x; gid < total;
       gid += gridDim.x * blockDim.x) {
    const float* src; short* dst; int off; float scl = 1.0f;
    if (gid < 3145728) {
      int z = gid >> 20;
      off = (gid & 1048575) << 2;
      src = (z == 0) ? q : (z == 1) ? k : v;
      dst = xb + (size_t)z * 4194304;
    } else {
      int g = gid - 3145728;
      int z = g >> 18;
      off = (g & 262143) << 2;
      src = (z == 0) ? wq : (z == 1) ? wk : (z == 2) ? wv : wo;
      dst = (z < 3) ? (wb + (size_t)z * 1048576) : wob;
      if (z == 0) scl = QSCALE;
    }
    fv4 f = *(const fv4*)(src + off);
    sv4 o;
    o.x = f2bf(f.x * scl); o.y = f2bf(f.y * scl);
    o.z = f2bf(f.z * scl); o.w = f2bf(f.w * scl);
    *(sv4*)(dst + off) = o;
  }
}

// ---------------------------------------------------------------------------
// Kernel 2/4: C = A @ W^T + bias.  128x128 tile, BK=64, 4 waves, 16x16x32.
// bf16 output path: C-tile routed through LDS (reusing the 32KB A/B staging
// buffer) -> 8 coalesced 16B stores/thread instead of 64 scalar b16 stores
// (32B-segment RMW writes were the suspected hidden cost).
// ---------------------------------------------------------------------------
__global__ __launch_bounds__(256) void gemm_bt(
    const short* __restrict__ Abase, const short* __restrict__ Wbase,
    const float* __restrict__ bias0, const float* __restrict__ bias1,
    const float* __restrict__ bias2, float bscl0,
    short* __restrict__ Cbf, float* __restrict__ Cf)
{
  const int Kd = 1024, Nd = 1024, Md = 4096;
  const int z = blockIdx.z;
  const short* A = Abase + (size_t)z * Md * Kd;
  const short* W = Wbase + (size_t)z * Nd * Kd;
  const float* bias = (z == 0) ? bias0 : (z == 1) ? bias1 : bias2;
  const float bscl = (z == 0) ? bscl0 : 1.0f;

  __shared__ short8 AB[2048];          // 32KB: As=AB[0:1024), Bs=AB[1024:2048)
  short8* As = AB;
  short8* Bs = AB + 1024;

  const int tid = threadIdx.x;
  const int w = tid >> 6, lane = tid & 63;
  const int wr = w >> 1, wc = w & 1;
  const int lhi = lane >> 4, llo = lane & 15;
  const int m0 = blockIdx.y * 128, n0 = blockIdx.x * 128;

  const f32x4 zero = {0.f, 0.f, 0.f, 0.f};
  f32x4 acc[4][4];
#pragma unroll
  for (int i = 0; i < 4; ++i)
#pragma unroll
    for (int j = 0; j < 4; ++j) acc[i][j] = zero;

  for (int kt = 0; kt < Kd / 64; ++kt) {
    const int k0 = kt * 64;
    __syncthreads();
#pragma unroll
    for (int inst = 0; inst < 4; ++inst) {
      int ib = w * 4096 + inst * 1024 + lane * 16;       // byte slot in 16KB tile
      int row = ib >> 7;                                 // 128B per row
      int colb = (ib & 127) ^ ((row & 7) << 4);          // inverse swizzle source
      int col = colb >> 1;
      GLL16(A + (size_t)(m0 + row) * Kd + k0 + col,
            (char*)As + (w * 4096 + inst * 1024));
      GLL16(W + (size_t)(n0 + row) * Kd + k0 + col,
            (char*)Bs + (w * 4096 + inst * 1024));
    }
    __syncthreads();
#pragma unroll
    for (int kk = 0; kk < 2; ++kk) {
      bf16x8 af[4], bfm[4];
#pragma unroll
      for (int t = 0; t < 4; ++t) {
        int arow = wr * 64 + t * 16 + llo;
        int abyte = ((arow << 7) + ((kk * 32 + lhi * 8) << 1)) ^ ((arow & 7) << 4);
        af[t] = ldfrag((const char*)As + abyte);
        int brow = wc * 64 + t * 16 + llo;
        int bbyte = ((brow << 7) + ((kk * 32 + lhi * 8) << 1)) ^ ((brow & 7) << 4);
        bfm[t] = ldfrag((const char*)Bs + bbyte);
      }
#pragma unroll
      for (int i = 0; i < 4; ++i)
#pragma unroll
        for (int j = 0; j < 4; ++j)
          acc[i][j] = __builtin_amdgcn_mfma_f32_16x16x32_bf16(af[i], bfm[j], acc[i][j], 0, 0, 0);
    }
  }

  if (Cbf) {
    // bf16 output: route through LDS for coalesced 16B stores
    short* Co = Cbf + (size_t)z * Md * Nd;
    __syncthreads();                       // all MFMA ds_reads of AB done
    short* Cs = (short*)AB;                // 128x128 bf16 = 32KB
#pragma unroll
    for (int i = 0; i < 4; ++i) {
#pragma unroll
      for (int j = 0; j < 4; ++j) {
        int col = wc * 64 + j * 16 + llo;
        float bv_ = bias[n0 + col] * bscl;
#pragma unroll
        for (int r = 0; r < 4; ++r) {
          int row = wr * 64 + i * 16 + lhi * 4 + r;
          Cs[row * 128 + col] = f2bf(acc[i][j][r] + bv_);
        }
      }
    }
    __syncthreads();
#pragma unroll
    for (int s = 0; s < 8; ++s) {
      int lb = s * 4096 + tid * 16;        // linear byte in 32KB tile
      short8 vL = *(const short8*)((const char*)Cs + lb);
      int row = lb >> 8;                   // 256B per row
      int colb = lb & 255;
      *(short8*)&Co[(size_t)(m0 + row) * Nd + n0 + (colb >> 1)] = vL;
    }
  } else {
    // f32 output: direct dword stores (64B segments per 16-lane group)
#pragma unroll
    for (int i = 0; i < 4; ++i) {
#pragma unroll
      for (int j = 0; j < 4; ++j) {
#pragma unroll
        for (int r = 0; r < 4; ++r) {
          int row = m0 + wr * 64 + i * 16 + lhi * 4 + r;
          int col = n0 + wc * 64 + j * 16 + llo;
          Cf[(size_t)row * Nd + col] = acc[i][j][r] + bias[col] * bscl;
        }
      }
    }
  }
}

// ---------------------------------------------------------------------------
// Kernel 3: causal flash attention, pipelined, all-resident.
// Flat grid 1024 blocks, 34KB LDS -> 4 blocks/CU.  Per-CU balance via 4-set
// qt mapping (66 tile-units per CU).  Double-buffered K (GLL, swizzled);
// single-buffered V^T (B2 barrier orders); conflict-free b16 V^T writes.
// Per tile: vmcnt(0); V^T write; issue next loads; lgkm+B1; QK; softmax
// (T13 defer-rescale); PV; B2.  Epilogue routed through LDS -> coalesced.
// ---------------------------------------------------------------------------
__global__ __launch_bounds__(256) void attn_fwd(
    const short* __restrict__ Qp, const short* __restrict__ Kp,
    const short* __restrict__ Vp, short* __restrict__ Out)
{
  __shared__ short8 Ks[2][512];      // 2 x 64x64 bf16, swizzled (16KB)
  __shared__ short  Vt[64 * 72];     // V^T 64 d-rows x 72-pad (9KB)
  __shared__ short  PsA[4][16 * 72]; // per-wave P (9KB)

  const int tid = threadIdx.x;
  const int w = tid >> 6, lane = tid & 63;
  const int lhi = lane >> 4, llo = lane & 15;

  // 4-set balanced decode
  const int id = blockIdx.x;
  const int g  = id & 255;           // CU slot under stride-256 round-robin
  const int kq = id >> 8;            // 0..3
  const int wv = g & 7;              // 4-set selector
  const int bh = g >> 3;             // 0..31
  const int qt = (kq == 0) ? 2 * wv : (kq == 1) ? 31 - 2 * wv
               : (kq == 2) ? 2 * wv + 1 : 30 - 2 * wv;
  const int nt = qt + 1;
  const int qbase = qt * 64;
  const int b = bh >> 4, h = bh & 15;
  const size_t rowbase = (size_t)b * S_LEN;
  const short* Kbase = Kp + rowbase * DMODEL + h * DKH;
  const short* Vbase = Vp + rowbase * DMODEL + h * DKH;

  short* Ps = PsA[w];
  const f32x4 zero = {0.f, 0.f, 0.f, 0.f};

  // Q fragments (registers for whole block)
  bf16x8 qf[2];
  {
    const short* qrow = Qp + (rowbase + qbase + w * 16 + llo) * DMODEL + h * DKH;
    qf[0] = ldfrag(qrow + lhi * 8);
    qf[1] = ldfrag(qrow + 32 + lhi * 8);
  }

  float mr[4], lr[4];
  f32x4 oacc[4];
#pragma unroll
  for (int r = 0; r < 4; ++r) { mr[r] = -3.0e38f; lr[r] = 0.f; }
#pragma unroll
  for (int dt = 0; dt < 4; ++dt) oacc[dt] = zero;

  // V staging assignment: kv = lane, d-group = wave (16 d per thread)
  const int kvs = lane, dgrp = w;

  // prologue: stage tile 0
#pragma unroll
  for (int inst = 0; inst < 2; ++inst) {
    int ib = w * 2048 + inst * 1024 + lane * 16;
    int row = ib >> 7;
    int colb = (ib & 127) ^ ((row & 7) << 4);
    GLL16(Kbase + (size_t)row * DMODEL + (colb >> 1),
          (char*)&Ks[0][0] + (w * 2048 + inst * 1024));
  }
  short8 va, vb;
  va = *(const short8*)(Vbase + (size_t)kvs * DMODEL + dgrp * 16);
  vb = *(const short8*)(Vbase + (size_t)kvs * DMODEL + dgrp * 16 + 8);

  for (int t = 0; t < nt; ++t) {
    const int cur = t & 1, nxt = cur ^ 1;
    const int kvbase = t * 64;

    WAIT_VMCNT0();   // own K-GLL(t) + V-regs(t) complete
    // write V^T(t): b16 scalar, kv contiguous across lanes -> conflict-free
    // single buffer: B2 of t-1 guarantees all PV reads of t-1 are done
#pragma unroll
    for (int j = 0; j < 8; ++j) Vt[(dgrp * 16 + j) * 72 + kvs] = va[j];
#pragma unroll
    for (int j = 0; j < 8; ++j) Vt[(dgrp * 16 + 8 + j) * 72 + kvs] = vb[j];
    // issue next-tile loads (stay in flight across compute)
    if (t + 1 < nt) {
      const int nb = kvbase + 64;
#pragma unroll
      for (int inst = 0; inst < 2; ++inst) {
        int ib = w * 2048 + inst * 1024 + lane * 16;
        int row = ib >> 7;
        int colb = (ib & 127) ^ ((row & 7) << 4);
        GLL16(Kbase + (size_t)(nb + row) * DMODEL + (colb >> 1),
              (char*)&Ks[nxt][0] + (w * 2048 + inst * 1024));
      }
      va = *(const short8*)(Vbase + (size_t)(nb + kvs) * DMODEL + dgrp * 16);
      vb = *(const short8*)(Vbase + (size_t)(nb + kvs) * DMODEL + dgrp * 16 + 8);
    }
    WAIT_LGKM0();
    __builtin_amdgcn_s_barrier();   // B1: all staging for tile t visible

    // QK^T
    f32x4 sc[4];
#pragma unroll
    for (int tt = 0; tt < 4; ++tt) sc[tt] = zero;
    __builtin_amdgcn_s_setprio(1);
#pragma unroll
    for (int kk = 0; kk < 2; ++kk) {
#pragma unroll
      for (int tt = 0; tt < 4; ++tt) {
        int krow = tt * 16 + llo;
        int kbyte = ((krow << 7) + ((kk * 32 + lhi * 8) << 1)) ^ ((krow & 7) << 4);
        bf16x8 kf = ldfrag((const char*)&Ks[cur][0] + kbyte);
        sc[tt] = __builtin_amdgcn_mfma_f32_16x16x32_bf16(qf[kk], kf, sc[tt], 0, 0, 0);
      }
    }
    __builtin_amdgcn_s_setprio(0);

    // mask + tile max (exp2 domain; scores pre-scaled via Wq)
    const bool diag = (t == qt);
    float sv[4][4], tmx[4];
#pragma unroll
    for (int r = 0; r < 4; ++r) {
#pragma unroll
      for (int tt = 0; tt < 4; ++tt) {
        float s = sc[tt][r];
        if (diag) {
          int kg = kvbase + tt * 16 + llo;
          int qg = qbase + w * 16 + lhi * 4 + r;
          if (kg > qg) s = -3.0e38f;
        }
        sv[tt][r] = s;
      }
      float trm = fmaxf(fmaxf(sv[0][r], sv[1][r]), fmaxf(sv[2][r], sv[3][r]));
      trm = fmaxf(trm, __shfl_xor(trm, 1));
      trm = fmaxf(trm, __shfl_xor(trm, 2));
      trm = fmaxf(trm, __shfl_xor(trm, 4));
      trm = fmaxf(trm, __shfl_xor(trm, 8));
      tmx[r] = trm;
    }
    // T13 defer-rescale: only rescale when some row's max grew past THR=8
    bool grow = (tmx[0] > mr[0] + 8.f) || (tmx[1] > mr[1] + 8.f) ||
                (tmx[2] > mr[2] + 8.f) || (tmx[3] > mr[3] + 8.f);
    if (__ballot(grow)) {
#pragma unroll
      for (int r = 0; r < 4; ++r) {
        float mnew = fmaxf(mr[r], tmx[r]);
        float alpha = __builtin_amdgcn_exp2f(mr[r] - mnew);
        mr[r] = mnew;
        lr[r] *= alpha;
#pragma unroll
        for (int dt = 0; dt < 4; ++dt) oacc[dt][r] = oacc[dt][r] * alpha;
      }
    }
#pragma unroll
    for (int r = 0; r < 4; ++r) {
      float rs = 0.f;
#pragma unroll
      for (int tt = 0; tt < 4; ++tt) {
        float pv = __builtin_amdgcn_exp2f(sv[tt][r] - mr[r]);
        rs += pv;
        Ps[(lhi * 4 + r) * 72 + tt * 16 + llo] = f2bf(pv);
      }
      rs += __shfl_xor(rs, 1);
      rs += __shfl_xor(rs, 2);
      rs += __shfl_xor(rs, 4);
      rs += __shfl_xor(rs, 8);
      lr[r] += rs;
    }

    // PV
    __builtin_amdgcn_s_setprio(1);
#pragma unroll
    for (int kk = 0; kk < 2; ++kk) {
      bf16x8 pa = ldfrag(Ps + llo * 72 + kk * 32 + lhi * 8);
#pragma unroll
      for (int dt = 0; dt < 4; ++dt) {
        bf16x8 vf = ldfrag(&Vt[(dt * 16 + llo) * 72 + kk * 32 + lhi * 8]);
        oacc[dt] = __builtin_amdgcn_mfma_f32_16x16x32_bf16(pa, vf, oacc[dt], 0, 0, 0);
      }
    }
    __builtin_amdgcn_s_setprio(0);
    __builtin_amdgcn_s_barrier();   // B2: reads of Ks[cur]/Vt done before reuse
  }

  // epilogue: normalize, route through per-wave LDS, coalesced 16B stores
#pragma unroll
  for (int dt = 0; dt < 4; ++dt)
#pragma unroll
    for (int r = 0; r < 4; ++r)
      Ps[(lhi * 4 + r) * 64 + dt * 16 + llo] = f2bf(oacc[dt][r] / lr[r]);
  WAIT_LGKM0();   // same-wave LDS write->read ordering (cross-lane)
#pragma unroll
  for (int s = 0; s < 2; ++s) {
    int lb = lane * 32 + s * 16;       // linear byte in 2KB wave tile
    short8 vL = *(const short8*)((const char*)Ps + lb);
    int row = lb >> 7;                 // 128B per row
    int colb = lb & 127;
    *(short8*)&Out[(rowbase + qbase + w * 16 + row) * DMODEL + h * DKH + (colb >> 1)] = vL;
  }
}

// ---------------------------------------------------------------------------
extern "C" void kernel_launch(void* const* d_in, const int* in_sizes, int n_in,
                              void* d_out, int out_size, void* d_ws, size_t ws_size,
                              hipStream_t stream) {
  (void)in_sizes; (void)n_in; (void)out_size; (void)ws_size;
  const float* q  = (const float*)d_in[0];
  const float* k  = (const float*)d_in[1];
  const float* v  = (const float*)d_in[2];
  // d_in[3] = causal mask (structure known, ignored)
  const float* Wq = (const float*)d_in[4];
  const float* bq = (const float*)d_in[5];
  const float* Wk = (const float*)d_in[6];
  const float* bk = (const float*)d_in[7];
  const float* Wv = (const float*)d_in[8];
  const float* bv = (const float*)d_in[9];
  const float* Wo = (const float*)d_in[10];
  const float* bo = (const float*)d_in[11];
  float* out = (float*)d_out;

  // workspace layout (bf16/short units), ~59MB total
  short* xb   = (short*)d_ws;              // 3 * 4194304 (q,k,v bf16)
  short* wb   = xb + 3ull * 4194304;       // 3 * 1048576 (Wq,Wk,Wv bf16; Wq pre-scaled)
  short* wob  = wb + 3ull * 1048576;       // 1048576    (Wo bf16)
  short* proj = wob + 1048576;             // 3 * 4194304 (Q,K,V projected)
  short* attno = xb;                       // reuse xb (free after projections)

  convert_all<<<dim3(2048), dim3(256), 0, stream>>>(q, k, v, Wq, Wk, Wv, Wo, xb, wb, wob);
  gemm_bt<<<dim3(8, 32, 3), dim3(256), 0, stream>>>(xb, wb, bq, bk, bv, QSCALE, proj, nullptr);
  attn_fwd<<<dim3(1024), dim3(256), 0, stream>>>(proj, proj + 4194304ull,
                                                 proj + 2ull * 4194304, attno);
  gemm_bt<<<dim3(8, 32, 1), dim3(256), 0, stream>>>(attno, wob, bo, bo, bo, 1.0f, nullptr, out);
}

// Round 8
// 256.399 us; speedup vs baseline: 1.1005x; 1.1005x over previous
//
#include <hip/hip_runtime.h>
#include <stdint.h>

// Problem constants
#define S_LEN 2048
#define DMODEL 1024
#define NHEAD 16
#define DKH 64
// M for all GEMMs = B*S = 4096, N = K = 1024

typedef __attribute__((ext_vector_type(8))) short short8;
typedef __attribute__((ext_vector_type(4))) short sv4;
typedef __attribute__((ext_vector_type(4))) float fv4;
typedef __attribute__((ext_vector_type(8))) __bf16 bf16x8;
typedef __attribute__((ext_vector_type(4))) float f32x4;

// 0.125 (1/sqrt(DK)) * log2(e): folded into Wq/bq so softmax can use native exp2
#define QSCALE 0.18033688011112042f

static __device__ __forceinline__ short f2bf(float f) {
  unsigned u = __builtin_bit_cast(unsigned, f);
  u = u + 0x7fffu + ((u >> 16) & 1u);   // RNE
  return (short)(u >> 16);
}

static __device__ __forceinline__ bf16x8 ldfrag(const void* p) {
  return __builtin_bit_cast(bf16x8, *(const short8*)p);
}

#define GLL16(gp, lp) __builtin_amdgcn_global_load_lds( \
    (const __attribute__((address_space(1))) unsigned int*)(const void*)(gp), \
    (__attribute__((address_space(3))) unsigned int*)(void*)(lp), 16, 0, 0)

#define WAIT_VMCNT0() asm volatile("s_waitcnt vmcnt(0)" ::: "memory")
#define WAIT_LGKM0()  asm volatile("s_waitcnt lgkmcnt(0)" ::: "memory")

// ---------------------------------------------------------------------------
// Kernel 1: f32 -> bf16 conversion of q,k,v and Wq,Wk,Wv,Wo.
// Wq is pre-scaled by QSCALE (softmax then uses exp2 with no per-elem scale).
// ---------------------------------------------------------------------------
__global__ __launch_bounds__(256) void convert_all(
    const float* __restrict__ q, const float* __restrict__ k, const float* __restrict__ v,
    const float* __restrict__ wq, const float* __restrict__ wk, const float* __restrict__ wv,
    const float* __restrict__ wo,
    short* __restrict__ xb, short* __restrict__ wb, short* __restrict__ wob)
{
  const int total = 4194304;  // float4 groups: 3*(4M/4) + 4*(1M/4)
  for (int gid = blockIdx.x * blockDim.x + threadIdx.x; gid < total;
       gid += gridDim.x * blockDim.x) {
    const float* src; short* dst; int off; float scl = 1.0f;
    if (gid < 3145728) {
      int z = gid >> 20;
      off = (gid & 1048575) << 2;
      src = (z == 0) ? q : (z == 1) ? k : v;
      dst = xb + (size_t)z * 4194304;
    } else {
      int g = gid - 3145728;
      int z = g >> 18;
      off = (g & 262143) << 2;
      src = (z == 0) ? wq : (z == 1) ? wk : (z == 2) ? wv : wo;
      dst = (z < 3) ? (wb + (size_t)z * 1048576) : wob;
      if (z == 0) scl = QSCALE;
    }
    fv4 f = *(const fv4*)(src + off);
    sv4 o;
    o.x = f2bf(f.x * scl); o.y = f2bf(f.y * scl);
    o.z = f2bf(f.z * scl); o.w = f2bf(f.w * scl);
    *(sv4*)(dst + off) = o;
  }
}

// ---------------------------------------------------------------------------
// Kernel 2: QKV projections.  C = A @ W^T + bias, bf16 out.  128x128 tile,
// BK=64, 4 waves.  XCD-chunked swizzle: XCD k owns m-panels [4k,4k+4) ->
// 1MB A + 2MB W per XCD L2.  C routed through LDS for coalesced stores.
// ---------------------------------------------------------------------------
__global__ __launch_bounds__(256) void gemm_proj(
    const short* __restrict__ Abase, const short* __restrict__ Wbase,
    const float* __restrict__ bias0, const float* __restrict__ bias1,
    const float* __restrict__ bias2, float bscl0,
    short* __restrict__ Cbf)
{
  const int Kd = 1024, Nd = 1024, Md = 4096;
  const int z = blockIdx.z;
  const short* A = Abase + (size_t)z * Md * Kd;
  const short* W = Wbase + (size_t)z * Nd * Kd;
  const float* bias = (z == 0) ? bias0 : (z == 1) ? bias1 : bias2;
  const float bscl = (z == 0) ? bscl0 : 1.0f;

  __shared__ short8 AB[2048];          // 32KB: As / Bs
  short8* As = AB;
  short8* Bs = AB + 1024;

  const int tid = threadIdx.x;
  const int w = tid >> 6, lane = tid & 63;
  const int wr = w >> 1, wc = w & 1;
  const int lhi = lane >> 4, llo = lane & 15;
  // XCD swizzle: id%8 = XCD -> give each XCD a contiguous m-range
  const int id = blockIdx.x + 8 * blockIdx.y;       // [0,256)
  const int sw = (id & 7) * 32 + (id >> 3);
  const int n0 = (sw & 7) * 128, m0 = (sw >> 3) * 128;

  const f32x4 zero = {0.f, 0.f, 0.f, 0.f};
  f32x4 acc[4][4];
#pragma unroll
  for (int i = 0; i < 4; ++i)
#pragma unroll
    for (int j = 0; j < 4; ++j) acc[i][j] = zero;

  for (int kt = 0; kt < Kd / 64; ++kt) {
    const int k0 = kt * 64;
    __syncthreads();
#pragma unroll
    for (int inst = 0; inst < 4; ++inst) {
      int ib = w * 4096 + inst * 1024 + lane * 16;
      int row = ib >> 7;
      int colb = (ib & 127) ^ ((row & 7) << 4);
      int col = colb >> 1;
      GLL16(A + (size_t)(m0 + row) * Kd + k0 + col,
            (char*)As + (w * 4096 + inst * 1024));
      GLL16(W + (size_t)(n0 + row) * Kd + k0 + col,
            (char*)Bs + (w * 4096 + inst * 1024));
    }
    __syncthreads();
#pragma unroll
    for (int kk = 0; kk < 2; ++kk) {
      bf16x8 af[4], bfm[4];
#pragma unroll
      for (int t = 0; t < 4; ++t) {
        int arow = wr * 64 + t * 16 + llo;
        int abyte = ((arow << 7) + ((kk * 32 + lhi * 8) << 1)) ^ ((arow & 7) << 4);
        af[t] = ldfrag((const char*)As + abyte);
        int brow = wc * 64 + t * 16 + llo;
        int bbyte = ((brow << 7) + ((kk * 32 + lhi * 8) << 1)) ^ ((brow & 7) << 4);
        bfm[t] = ldfrag((const char*)Bs + bbyte);
      }
#pragma unroll
      for (int i = 0; i < 4; ++i)
#pragma unroll
        for (int j = 0; j < 4; ++j)
          acc[i][j] = __builtin_amdgcn_mfma_f32_16x16x32_bf16(af[i], bfm[j], acc[i][j], 0, 0, 0);
    }
  }

  // bf16 output: route through LDS for coalesced 16B stores
  short* Co = Cbf + (size_t)z * Md * Nd;
  __syncthreads();
  short* Cs = (short*)AB;                // 128x128 bf16 = 32KB
#pragma unroll
  for (int i = 0; i < 4; ++i) {
#pragma unroll
    for (int j = 0; j < 4; ++j) {
      int col = wc * 64 + j * 16 + llo;
      float bv_ = bias[n0 + col] * bscl;
#pragma unroll
      for (int r = 0; r < 4; ++r) {
        int row = wr * 64 + i * 16 + lhi * 4 + r;
        Cs[row * 128 + col] = f2bf(acc[i][j][r] + bv_);
      }
    }
  }
  __syncthreads();
#pragma unroll
  for (int s = 0; s < 8; ++s) {
    int lb = s * 4096 + tid * 16;
    short8 vL = *(const short8*)((const char*)Cs + lb);
    int row = lb >> 8;
    int colb = lb & 255;
    *(short8*)&Co[(size_t)(m0 + row) * Nd + n0 + (colb >> 1)] = vL;
  }
}

// ---------------------------------------------------------------------------
// Kernel 4: output projection.  C = A @ Wo^T + bo, f32 out.  128x64 tile
// (512 blocks = 2/CU for inter-block overlap), BK=64, 4 waves (2M x 2N,
// wave tile 64x32), 24KB LDS.  XCD-chunked swizzle as above.
// ---------------------------------------------------------------------------
__global__ __launch_bounds__(256) void gemm_out(
    const short* __restrict__ A, const short* __restrict__ W,
    const float* __restrict__ bias, float* __restrict__ Cf)
{
  const int Kd = 1024, Nd = 1024;

  __shared__ short8 As[1024];   // 128x64 bf16 (16KB)
  __shared__ short8 Bs[512];    // 64x64 bf16 (8KB)

  const int tid = threadIdx.x;
  const int w = tid >> 6, lane = tid & 63;
  const int wr = w >> 1, wc = w & 1;
  const int lhi = lane >> 4, llo = lane & 15;
  const int id = blockIdx.x + 16 * blockIdx.y;      // [0,512)
  const int sw = (id & 7) * 64 + (id >> 3);
  const int n0 = (sw & 15) * 64, m0 = (sw >> 4) * 128;

  const f32x4 zero = {0.f, 0.f, 0.f, 0.f};
  f32x4 acc[4][2];
#pragma unroll
  for (int i = 0; i < 4; ++i)
#pragma unroll
    for (int j = 0; j < 2; ++j) acc[i][j] = zero;

  for (int kt = 0; kt < Kd / 64; ++kt) {
    const int k0 = kt * 64;
    __syncthreads();
#pragma unroll
    for (int inst = 0; inst < 4; ++inst) {
      int ib = w * 4096 + inst * 1024 + lane * 16;
      int row = ib >> 7;
      int colb = (ib & 127) ^ ((row & 7) << 4);
      GLL16(A + (size_t)(m0 + row) * Kd + k0 + (colb >> 1),
            (char*)As + (w * 4096 + inst * 1024));
    }
#pragma unroll
    for (int inst = 0; inst < 2; ++inst) {
      int ib = w * 2048 + inst * 1024 + lane * 16;
      int row = ib >> 7;
      int colb = (ib & 127) ^ ((row & 7) << 4);
      GLL16(W + (size_t)(n0 + row) * Kd + k0 + (colb >> 1),
            (char*)Bs + (w * 2048 + inst * 1024));
    }
    __syncthreads();
#pragma unroll
    for (int kk = 0; kk < 2; ++kk) {
      bf16x8 af[4], bfm[2];
#pragma unroll
      for (int t = 0; t < 4; ++t) {
        int arow = wr * 64 + t * 16 + llo;
        int abyte = ((arow << 7) + ((kk * 32 + lhi * 8) << 1)) ^ ((arow & 7) << 4);
        af[t] = ldfrag((const char*)As + abyte);
      }
#pragma unroll
      for (int j = 0; j < 2; ++j) {
        int brow = wc * 32 + j * 16 + llo;
        int bbyte = ((brow << 7) + ((kk * 32 + lhi * 8) << 1)) ^ ((brow & 7) << 4);
        bfm[j] = ldfrag((const char*)Bs + bbyte);
      }
#pragma unroll
      for (int i = 0; i < 4; ++i)
#pragma unroll
        for (int j = 0; j < 2; ++j)
          acc[i][j] = __builtin_amdgcn_mfma_f32_16x16x32_bf16(af[i], bfm[j], acc[i][j], 0, 0, 0);
    }
  }

#pragma unroll
  for (int i = 0; i < 4; ++i) {
#pragma unroll
    for (int j = 0; j < 2; ++j) {
      int col = n0 + wc * 32 + j * 16 + llo;
      float bv_ = bias[col];
#pragma unroll
      for (int r = 0; r < 4; ++r) {
        int row = m0 + wr * 64 + i * 16 + lhi * 4 + r;
        Cf[(size_t)row * Nd + col] = acc[i][j][r] + bv_;
      }
    }
  }
}

// ---------------------------------------------------------------------------
// Kernel 3: causal flash attention, pipelined, all-resident.
// Flat grid 1024 blocks, 34KB LDS -> 4 blocks/CU.  Per-CU balance via 4-set
// qt mapping (66 tile-units per CU).  Double-buffered K (GLL, swizzled);
// single-buffered V^T; conflict-free b16 V^T writes.  Per tile: vmcnt(0);
// V^T write; issue next loads; lgkm+B1; QK; softmax (T13 defer-rescale,
// l-reduce deferred to end); PV; B2.  Direct-store epilogue (R6 form).
// ---------------------------------------------------------------------------
__global__ __launch_bounds__(256) void attn_fwd(
    const short* __restrict__ Qp, const short* __restrict__ Kp,
    const short* __restrict__ Vp, short* __restrict__ Out)
{
  __shared__ short8 Ks[2][512];      // 2 x 64x64 bf16, swizzled (16KB)
  __shared__ short  Vt[64 * 72];     // V^T 64 d-rows x 72-pad (9KB)
  __shared__ short  PsA[4][16 * 72]; // per-wave P (9KB)

  const int tid = threadIdx.x;
  const int w = tid >> 6, lane = tid & 63;
  const int lhi = lane >> 4, llo = lane & 15;

  // 4-set balanced decode
  const int id = blockIdx.x;
  const int g  = id & 255;
  const int kq = id >> 8;
  const int wv = g & 7;
  const int bh = g >> 3;
  const int qt = (kq == 0) ? 2 * wv : (kq == 1) ? 31 - 2 * wv
               : (kq == 2) ? 2 * wv + 1 : 30 - 2 * wv;
  const int nt = qt + 1;
  const int qbase = qt * 64;
  const int b = bh >> 4, h = bh & 15;
  const size_t rowbase = (size_t)b * S_LEN;
  const short* Kbase = Kp + rowbase * DMODEL + h * DKH;
  const short* Vbase = Vp + rowbase * DMODEL + h * DKH;

  short* Ps = PsA[w];
  const f32x4 zero = {0.f, 0.f, 0.f, 0.f};

  // Q fragments (registers for whole block)
  bf16x8 qf[2];
  {
    const short* qrow = Qp + (rowbase + qbase + w * 16 + llo) * DMODEL + h * DKH;
    qf[0] = ldfrag(qrow + lhi * 8);
    qf[1] = ldfrag(qrow + 32 + lhi * 8);
  }

  float mr[4], lr[4];
  f32x4 oacc[4];
#pragma unroll
  for (int r = 0; r < 4; ++r) { mr[r] = -3.0e38f; lr[r] = 0.f; }
#pragma unroll
  for (int dt = 0; dt < 4; ++dt) oacc[dt] = zero;

  // V staging assignment: kv = lane, d-group = wave (16 d per thread)
  const int kvs = lane, dgrp = w;

  // prologue: stage tile 0
#pragma unroll
  for (int inst = 0; inst < 2; ++inst) {
    int ib = w * 2048 + inst * 1024 + lane * 16;
    int row = ib >> 7;
    int colb = (ib & 127) ^ ((row & 7) << 4);
    GLL16(Kbase + (size_t)row * DMODEL + (colb >> 1),
          (char*)&Ks[0][0] + (w * 2048 + inst * 1024));
  }
  short8 va, vb;
  va = *(const short8*)(Vbase + (size_t)kvs * DMODEL + dgrp * 16);
  vb = *(const short8*)(Vbase + (size_t)kvs * DMODEL + dgrp * 16 + 8);

  for (int t = 0; t < nt; ++t) {
    const int cur = t & 1, nxt = cur ^ 1;
    const int kvbase = t * 64;

    WAIT_VMCNT0();   // own K-GLL(t) + V-regs(t) complete
#pragma unroll
    for (int j = 0; j < 8; ++j) Vt[(dgrp * 16 + j) * 72 + kvs] = va[j];
#pragma unroll
    for (int j = 0; j < 8; ++j) Vt[(dgrp * 16 + 8 + j) * 72 + kvs] = vb[j];
    if (t + 1 < nt) {
      const int nb = kvbase + 64;
#pragma unroll
      for (int inst = 0; inst < 2; ++inst) {
        int ib = w * 2048 + inst * 1024 + lane * 16;
        int row = ib >> 7;
        int colb = (ib & 127) ^ ((row & 7) << 4);
        GLL16(Kbase + (size_t)(nb + row) * DMODEL + (colb >> 1),
              (char*)&Ks[nxt][0] + (w * 2048 + inst * 1024));
      }
      va = *(const short8*)(Vbase + (size_t)(nb + kvs) * DMODEL + dgrp * 16);
      vb = *(const short8*)(Vbase + (size_t)(nb + kvs) * DMODEL + dgrp * 16 + 8);
    }
    WAIT_LGKM0();
    __builtin_amdgcn_s_barrier();   // B1: all staging for tile t visible

    // QK^T
    f32x4 sc[4];
#pragma unroll
    for (int tt = 0; tt < 4; ++tt) sc[tt] = zero;
    __builtin_amdgcn_s_setprio(1);
#pragma unroll
    for (int kk = 0; kk < 2; ++kk) {
#pragma unroll
      for (int tt = 0; tt < 4; ++tt) {
        int krow = tt * 16 + llo;
        int kbyte = ((krow << 7) + ((kk * 32 + lhi * 8) << 1)) ^ ((krow & 7) << 4);
        bf16x8 kf = ldfrag((const char*)&Ks[cur][0] + kbyte);
        sc[tt] = __builtin_amdgcn_mfma_f32_16x16x32_bf16(qf[kk], kf, sc[tt], 0, 0, 0);
      }
    }
    __builtin_amdgcn_s_setprio(0);

    // mask + tile max (exp2 domain; scores pre-scaled via Wq)
    const bool diag = (t == qt);
    float sv[4][4], tmx[4];
#pragma unroll
    for (int r = 0; r < 4; ++r) {
#pragma unroll
      for (int tt = 0; tt < 4; ++tt) {
        float s = sc[tt][r];
        if (diag) {
          int kg = kvbase + tt * 16 + llo;
          int qg = qbase + w * 16 + lhi * 4 + r;
          if (kg > qg) s = -3.0e38f;
        }
        sv[tt][r] = s;
      }
      float trm = fmaxf(fmaxf(sv[0][r], sv[1][r]), fmaxf(sv[2][r], sv[3][r]));
      trm = fmaxf(trm, __shfl_xor(trm, 1));
      trm = fmaxf(trm, __shfl_xor(trm, 2));
      trm = fmaxf(trm, __shfl_xor(trm, 4));
      trm = fmaxf(trm, __shfl_xor(trm, 8));
      tmx[r] = trm;
    }
    // T13 defer-rescale
    bool grow = (tmx[0] > mr[0] + 8.f) || (tmx[1] > mr[1] + 8.f) ||
                (tmx[2] > mr[2] + 8.f) || (tmx[3] > mr[3] + 8.f);
    if (__ballot(grow)) {
#pragma unroll
      for (int r = 0; r < 4; ++r) {
        float mnew = fmaxf(mr[r], tmx[r]);
        float alpha = __builtin_amdgcn_exp2f(mr[r] - mnew);
        mr[r] = mnew;
        lr[r] *= alpha;
#pragma unroll
        for (int dt = 0; dt < 4; ++dt) oacc[dt][r] = oacc[dt][r] * alpha;
      }
    }
    // P + per-lane partial l (reduce deferred to end — linear under alpha)
#pragma unroll
    for (int r = 0; r < 4; ++r) {
      float rs = 0.f;
#pragma unroll
      for (int tt = 0; tt < 4; ++tt) {
        float pv = __builtin_amdgcn_exp2f(sv[tt][r] - mr[r]);
        rs += pv;
        Ps[(lhi * 4 + r) * 72 + tt * 16 + llo] = f2bf(pv);
      }
      lr[r] += rs;
    }

    // PV
    __builtin_amdgcn_s_setprio(1);
#pragma unroll
    for (int kk = 0; kk < 2; ++kk) {
      bf16x8 pa = ldfrag(Ps + llo * 72 + kk * 32 + lhi * 8);
#pragma unroll
      for (int dt = 0; dt < 4; ++dt) {
        bf16x8 vf = ldfrag(&Vt[(dt * 16 + llo) * 72 + kk * 32 + lhi * 8]);
        oacc[dt] = __builtin_amdgcn_mfma_f32_16x16x32_bf16(pa, vf, oacc[dt], 0, 0, 0);
      }
    }
    __builtin_amdgcn_s_setprio(0);
    __builtin_amdgcn_s_barrier();   // B2: reads of Ks[cur]/Vt done before reuse
  }

  // final l reduction (was per-tile), then direct-store epilogue
#pragma unroll
  for (int r = 0; r < 4; ++r) {
    float rs = lr[r];
    rs += __shfl_xor(rs, 1);
    rs += __shfl_xor(rs, 2);
    rs += __shfl_xor(rs, 4);
    rs += __shfl_xor(rs, 8);
    lr[r] = rs;
  }
#pragma unroll
  for (int dt = 0; dt < 4; ++dt) {
#pragma unroll
    for (int r = 0; r < 4; ++r) {
      float vv = oacc[dt][r] / lr[r];
      int row = qbase + w * 16 + lhi * 4 + r;
      int col = h * DKH + dt * 16 + llo;
      Out[(rowbase + row) * DMODEL + col] = f2bf(vv);
    }
  }
}

// ---------------------------------------------------------------------------
extern "C" void kernel_launch(void* const* d_in, const int* in_sizes, int n_in,
                              void* d_out, int out_size, void* d_ws, size_t ws_size,
                              hipStream_t stream) {
  (void)in_sizes; (void)n_in; (void)out_size; (void)ws_size;
  const float* q  = (const float*)d_in[0];
  const float* k  = (const float*)d_in[1];
  const float* v  = (const float*)d_in[2];
  // d_in[3] = causal mask (structure known, ignored)
  const float* Wq = (const float*)d_in[4];
  const float* bq = (const float*)d_in[5];
  const float* Wk = (const float*)d_in[6];
  const float* bk = (const float*)d_in[7];
  const float* Wv = (const float*)d_in[8];
  const float* bv = (const float*)d_in[9];
  const float* Wo = (const float*)d_in[10];
  const float* bo = (const float*)d_in[11];
  float* out = (float*)d_out;

  // workspace layout (bf16/short units), ~59MB total
  short* xb   = (short*)d_ws;              // 3 * 4194304 (q,k,v bf16)
  short* wb   = xb + 3ull * 4194304;       // 3 * 1048576 (Wq,Wk,Wv bf16; Wq pre-scaled)
  short* wob  = wb + 3ull * 1048576;       // 1048576    (Wo bf16)
  short* proj = wob + 1048576;             // 3 * 4194304 (Q,K,V projected)
  short* attno = xb;                       // reuse xb (free after projections)

  convert_all<<<dim3(2048), dim3(256), 0, stream>>>(q, k, v, Wq, Wk, Wv, Wo, xb, wb, wob);
  gemm_proj<<<dim3(8, 32, 3), dim3(256), 0, stream>>>(xb, wb, bq, bk, bv, QSCALE, proj);
  attn_fwd<<<dim3(1024), dim3(256), 0, stream>>>(proj, proj + 4194304ull,
                                                 proj + 2ull * 4194304, attno);
  gemm_out<<<dim3(16, 32), dim3(256), 0, stream>>>(attno, wob, bo, out);
}